// Round 15
// baseline (225.576 us; speedup 1.0000x reference)
//
#include <hip/hip_runtime.h>

#define NPTS    131072     // 32 * 64 * 64 points
#define KC      1024       // codes
#define DD      64         // embedding dim
#define HWSZ    4096       // h*w
#define MARGINF 6e-5f      // packed-domain gap below which we refine on the f32 grid
#define SLACKF  4e-5f      // f32-filter slack >= 2*(chain err ~2e-6 + ulp(64) 7.6e-6)

typedef __attribute__((ext_vector_type(8))) short short8;  // 8 bf16 = 4 VGPRs
typedef __attribute__((ext_vector_type(4))) float f32x4;   // MFMA C/D frag

__device__ __forceinline__ ushort bf16_rne(float x) {
    unsigned u = __float_as_uint(x);
    unsigned r = u + 0x7fffu + ((u >> 16) & 1u);
    return (ushort)(r >> 16);
}

__device__ __forceinline__ float rdlane(float v, int d) {
    return __int_as_float(__builtin_amdgcn_readlane(__float_as_int(v), d));
}

// exact per-code grid value: ascending-d serial f64 fma chain + single rounding
// (bit-identical op order to the r3-verified vq_fix path).
__device__ __forceinline__ float exact_dv(float xrv, const float* __restrict__ emb,
                                          const float* __restrict__ se32,
                                          float sx, int k) {
    const float* er = emb + k * DD;
    double a = 0.0;
#pragma unroll 4
    for (int d = 0; d < DD; ++d)
        a = fma((double)rdlane(xrv, d), (double)er[d], a);
    float mm = (float)(2.0 * a);          // single rounding
    float s1, Dv;
    {
#pragma clang fp contract(off)
        s1 = sx + se32[k];
        Dv = s1 - mm;                     // the reference's f32 grid value
    }
    return Dv;
}

// ---- E prep: 64 blocks x 256 threads, one 16-code tile per block.
// All global loads/stores coalesced; ||e||^2 array-free in numpy pairwise order.
__global__ void __launch_bounds__(256)
vq_prep_e(const float* __restrict__ emb, float* __restrict__ se32,
          float* __restrict__ sebB, ushort* __restrict__ Ebuf,
          float* __restrict__ embT, int* __restrict__ cnt) {
    __shared__ float es[16][68];        // 16 codes x 64 dims, pad -> conflict-light
    const int tid  = threadIdx.x;       // 0..255
    const int tile = blockIdx.x;        // 64 tiles of 16 codes
    const int kbase = tile * 16;

    if (tile == 0 && tid == 0) *cnt = 0;   // replaces the memset dispatch

    // stage 16x64 floats coalesced (4 x 256 lanes, consecutive addresses)
#pragma unroll
    for (int it = 0; it < 4; ++it) {
        int f = it * 256 + tid;         // 0..1023
        es[f >> 6][f & 63] = emb[(size_t)kbase * DD + f];
    }
    __syncthreads();

    // ||e||^2: one thread per code, numpy pairwise order, registers only
    if (tid < 16) {
        float rr[8];
#pragma unroll
        for (int di = 0; di < 8; ++di) rr[di] = 0.0f;
        {
#pragma clang fp contract(off)
#pragma unroll
            for (int dm = 0; dm < 8; ++dm)
#pragma unroll
                for (int di = 0; di < 8; ++di) {
                    float ev = es[tid][dm * 8 + di];
                    rr[di] += ev * ev;      // 0+t == t bitwise (squares are +0-signed)
                }
        }
        float s;
        {
#pragma clang fp contract(off)
            s = ((rr[0] + rr[1]) + (rr[2] + rr[3])) + ((rr[4] + rr[5]) + (rr[6] + rr[7]));
        }
        se32[kbase + tid] = s;
        sebB[kbase + tid] = s + 0.5f;   // bias keeps scan scores strictly positive
    }

    // embT[d][k]: 1024 elems, 16-float runs contiguous -> well-coalesced
#pragma unroll
    for (int it = 0; it < 4; ++it) {
        int f = it * 256 + tid;
        int d = f >> 4, colk = f & 15;
        embT[d * KC + kbase + colk] = es[colk][d];
    }

    // Ebuf: 4 sub-blocks (kh,hl) x 512 ushorts, fully coalesced stores.
#pragma unroll
    for (int it = 0; it < 8; ++it) {
        int f = it * 256 + tid;         // 0..2047
        int sub = f >> 9;               // kh*2 + hl
        int pos = f & 511;
        int kh = sub >> 1, hl = sub & 1;
        int jj = pos & 7, colk = (pos >> 3) & 15, quad = pos >> 7;
        float ev = es[colk][kh * 32 + quad * 8 + jj];
        ushort hb = bf16_rne(ev);
        ushort val;
        if (hl == 0) {
            val = hb;
        } else {
            float hf = __uint_as_float(((unsigned)hb) << 16);
            val = bf16_rne(ev - hf);
        }
        Ebuf[((tile * 2 + kh) * 2 + hl) * 512 + pos] = val;
    }
}

// ---- fused: stage x -> A frags -> MFMA scan (packed-uint argmin) -> outputs
// NEW (this round): B staged per-block into LDS (double-buffered, async
// global_load_lds width-16) instead of each of 4 waves re-reading the same
// 16KB g-block from L2. Bytes are bit-identical; L2 B-traffic /4; B-frag
// reads become ds_read_b128 at immediate offsets.
__global__ void __launch_bounds__(256)
vq_main(const float* __restrict__ in, const float* __restrict__ emb,
        const ushort* __restrict__ Ebuf, const float* __restrict__ sebB,
        float* __restrict__ outq, float* __restrict__ outl, float* __restrict__ outi,
        int* __restrict__ cnt, int* __restrict__ queue) {
    __shared__ float xs[64][129];   // [c][j], pad -> conflict-light both ways (33 KB)
    __shared__ int   sidx[128];
    __shared__ ushort Bs[2][8192];  // double-buffered 16KB B g-block (32 KB)
    const int tid = threadIdx.x;
    const int n0  = blockIdx.x * 128;     // 128 consecutive points, single batch image
    const int b   = n0 >> 12;
    const int hw0 = n0 & 4095;
    const float* inb = in + (size_t)b * DD * HWSZ;

    // stage exact x for the block's 128 points (coalesced over hw)
#pragma unroll
    for (int it = 0; it < 32; ++it) {
        int f = tid + it * 256;
        int c = f >> 7, j = f & 127;
        xs[c][j] = inb[c * HWSZ + hw0 + j];
    }
    __syncthreads();

    const int lane = tid & 63, wave = tid >> 6;
    const int quad = lane >> 4, col = lane & 15;

    // A fragments (bf16 hi/lo) straight from LDS — no global X roundtrip
    short8 A[2][2][2];   // [psub][khalf][hi/lo]
#pragma unroll
    for (int p = 0; p < 2; ++p) {
        int pt = wave * 32 + p * 16 + col;
#pragma unroll
        for (int kh = 0; kh < 2; ++kh) {
            short8 ah, al;
#pragma unroll
            for (int j = 0; j < 8; ++j) {
                float xv = xs[kh * 32 + quad * 8 + j][pt];
                ushort hb = bf16_rne(xv);
                float  hf = __uint_as_float(((unsigned)hb) << 16);
                ah[j] = (short)hb;
                al[j] = (short)bf16_rne(xv - hf);
            }
            A[p][kh][0] = ah; A[p][kh][1] = al;
        }
    }

    unsigned b1[8], b2[8];          // packed: (score+0.5 bits & ~63) | tile
#pragma unroll
    for (int s = 0; s < 8; ++s) { b1[s] = 0xFFFFFFFFu; b2[s] = 0xFFFFFFFFu; }

    // prologue: stage g=0 B-block (each wave stages 4 x 1KB sub-blocks)
    {
        const ushort* src = Ebuf;           // g = 0
#pragma unroll
        for (int j = 0; j < 4; ++j) {
            int sb = wave * 4 + j;          // 0..15
            __builtin_amdgcn_global_load_lds(
                (const __attribute__((address_space(1))) void*)(src + sb * 512 + lane * 8),
                (__attribute__((address_space(3))) void*)(&Bs[0][sb * 512]),
                16, 0, 0);
        }
    }
    __syncthreads();    // compiler drains vmcnt(0) before s_barrier -> Bs[0] ready

    for (int g = 0; g < 16; ++g) {            // 64 codes per iteration
        const int cur = g & 1;
        if (g < 15) {                         // prefetch next g-block into other buf
            const ushort* src = Ebuf + (g + 1) * 8192;
#pragma unroll
            for (int j = 0; j < 4; ++j) {
                int sb = wave * 4 + j;
                __builtin_amdgcn_global_load_lds(
                    (const __attribute__((address_space(1))) void*)(src + sb * 512 + lane * 8),
                    (__attribute__((address_space(3))) void*)(&Bs[cur ^ 1][sb * 512]),
                    16, 0, 0);
            }
        }

        short8 B[4][2][2];
        float  sB[4];
#pragma unroll
        for (int s = 0; s < 4; ++s) {
            int tile = g * 4 + s;
            sB[s] = sebB[tile * 16 + col];
#pragma unroll
            for (int kh = 0; kh < 2; ++kh)
#pragma unroll
                for (int hl = 0; hl < 2; ++hl)
                    B[s][kh][hl] = *(const short8*)&Bs[cur][((s * 2 + kh) * 2 + hl) * 512 + lane * 8];
        }
        f32x4 acc[2][4];
#pragma unroll
        for (int p = 0; p < 2; ++p)
#pragma unroll
            for (int s = 0; s < 4; ++s) acc[p][s] = (f32x4){0.f, 0.f, 0.f, 0.f};
#pragma unroll
        for (int p = 0; p < 2; ++p)
#pragma unroll
            for (int s = 0; s < 4; ++s) {
                acc[p][s] = __builtin_amdgcn_mfma_f32_16x16x32_bf16(A[p][0][0], B[s][0][0], acc[p][s], 0, 0, 0);
                acc[p][s] = __builtin_amdgcn_mfma_f32_16x16x32_bf16(A[p][1][0], B[s][1][0], acc[p][s], 0, 0, 0);
                acc[p][s] = __builtin_amdgcn_mfma_f32_16x16x32_bf16(A[p][0][0], B[s][0][1], acc[p][s], 0, 0, 0);
                acc[p][s] = __builtin_amdgcn_mfma_f32_16x16x32_bf16(A[p][1][0], B[s][1][1], acc[p][s], 0, 0, 0);
                acc[p][s] = __builtin_amdgcn_mfma_f32_16x16x32_bf16(A[p][0][1], B[s][0][0], acc[p][s], 0, 0, 0);
                acc[p][s] = __builtin_amdgcn_mfma_f32_16x16x32_bf16(A[p][1][1], B[s][1][0], acc[p][s], 0, 0, 0);
            }
        // packed-uint fold: 4 codes per slot via sorted-2-of-4 insertion
#pragma unroll
        for (int p = 0; p < 2; ++p)
#pragma unroll
            for (int r = 0; r < 4; ++r) {
                unsigned q[4];
#pragma unroll
                for (int s = 0; s < 4; ++s) {
                    float t = fmaf(-2.f, acc[p][s][r], sB[s]);       // 0.5 + se - 2x.e > 0
                    q[s] = (__float_as_uint(t) & 0xFFFFFFC0u) | (unsigned)(g * 4 + s);
                }
                unsigned a  = min(q[0], q[1]), bb = max(q[0], q[1]);
                unsigned c2 = min(q[2], q[3]), d2 = max(q[2], q[3]);
                unsigned lo = min(a, c2), hi = max(a, c2);
                unsigned sec = min(min(bb, d2), hi);                  // 2nd smallest of 4
                int sl = p * 4 + r;
                b2[sl] = min(min(b2[sl], sec), max(b1[sl], lo));
                b1[sl] = min(b1[sl], lo);
            }

        __syncthreads();   // drains prefetch (vmcnt0) + orders reads before overwrite
    }

    // decode + 16-col butterfly merge (first-index tie-break)
    unsigned v1[8], v2[8]; int ci[8];
#pragma unroll
    for (int s = 0; s < 8; ++s) {
        ci[s] = (int)(b1[s] & 63u) * 16 + col;
        v1[s] = b1[s] & 0xFFFFFFC0u;
        v2[s] = b2[s] & 0xFFFFFFC0u;
    }
#pragma unroll
    for (int off = 1; off < 16; off <<= 1) {
#pragma unroll
        for (int s = 0; s < 8; ++s) {
            unsigned o1 = (unsigned)__shfl_xor((int)v1[s], off);
            unsigned o2 = (unsigned)__shfl_xor((int)v2[s], off);
            int      oi = __shfl_xor(ci[s], off);
            unsigned nb2 = min(min(v2[s], o2), max(v1[s], o1));
            bool take = (o1 < v1[s]) || (o1 == v1[s] && oi < ci[s]);
            v1[s] = take ? o1 : v1[s];
            ci[s] = take ? oi : ci[s];
            v2[s] = nb2;
        }
    }
#pragma unroll
    for (int s = 0; s < 8; ++s) {
        if (col == s) {
            int jloc = wave * 32 + (s >> 2) * 16 + quad * 4 + (s & 3);
            sidx[jloc] = ci[s];
            float f1 = __uint_as_float(v1[s]), f2 = __uint_as_float(v2[s]);
            if (f2 - f1 < MARGINF) { int pos = atomicAdd(cnt, 1); queue[pos] = n0 + jloc; }
        }
    }
    __syncthreads();

    // fused output epilogue: lane -> channel, loop over this wave's 32 points
    for (int t = 0; t < 32; ++t) {
        int jloc = wave * 32 + t;
        int kidx = sidx[jloc];
        float qv = emb[kidx * DD + lane];              // coalesced 256B row, L2-hot
        float x  = xs[lane][jloc];
        float dv = qv - x;
        float l  = dv * dv;
        outl[(size_t)(n0 + jloc) * DD + lane] = fmaf(0.25f, l, l);   // coalesced
        outq[((size_t)(b * DD) + lane) * HWSZ + hw0 + jloc] = x + (qv - x);  // L2-merged scatter
    }
    if (lane < 32) outi[n0 + wave * 32 + lane] = (float)sidx[wave * 32 + lane];
}

// ---- fix v4: f32 filter with per-lane TOP-3 tracking -> explicit candidates
// {i1,i2} (<= gmin+SLACK) verified by the bit-exact serial f64 chain; full-16
// per-lane fallback only if m3 <= thr. Grid 2048 blocks.
__global__ void __launch_bounds__(256)
vq_fix(const float* __restrict__ in, const float* __restrict__ emb,
       const float* __restrict__ embT, const float* __restrict__ se32,
       const int* __restrict__ queue, const int* __restrict__ cnt,
       float* __restrict__ outq, float* __restrict__ outl, float* __restrict__ outi) {
    const int lane = threadIdx.x & 63;
    const int gw   = blockIdx.x * 4 + (threadIdx.x >> 6);
    const int nwav = gridDim.x * 4;
    const int total = *cnt;
    for (int q0 = gw * 4; q0 < total; q0 += nwav * 4) {
        int   nn[4]; bool vld[4];
        float xr[4], sx4[4];
#pragma unroll
        for (int i = 0; i < 4; ++i) {
            int qi = q0 + i;
            vld[i] = (qi < total);
            nn[i]  = queue[vld[i] ? qi : q0];
            int b = nn[i] >> 12, hw = nn[i] & 4095;
            xr[i] = in[(size_t)b * DD * HWSZ + (size_t)lane * HWSZ + hw]; // lane d holds x[d]
        }
        // ||x||^2 per point, numpy pairwise order (readlane ascending d) — exact
#pragma unroll
        for (int i = 0; i < 4; ++i) {
            float rr[8];
#pragma unroll
            for (int di = 0; di < 8; ++di) rr[di] = 0.0f;
            for (int dm = 0; dm < 8; ++dm) {
#pragma unroll
                for (int di = 0; di < 8; ++di) {
                    float xv = rdlane(xr[i], dm * 8 + di);
                    {
#pragma clang fp contract(off)
                        rr[di] += xv * xv;     // +0 init: 0+t == t bitwise, order kept
                    }
                }
            }
            {
#pragma clang fp contract(off)
                sx4[i] = ((rr[0] + rr[1]) + (rr[2] + rr[3])) + ((rr[4] + rr[5]) + (rr[6] + rr[7]));
            }
        }

        float m1[4], m2[4], m3[4]; int i1[4], i2[4];
#pragma unroll
        for (int i = 0; i < 4; ++i) {
            m1[i] = 3.4e38f; m2[i] = 3.4e38f; m3[i] = 3.4e38f;
            i1[i] = 0x7fffffff; i2[i] = 0x7fffffff;
        }

        // f32 filter: 4 passes of 4 codes/lane; 16 live f32 accumulators
        for (int pass = 0; pass < 4; ++pass) {
            float acc[16];
#pragma unroll
            for (int a = 0; a < 16; ++a) acc[a] = 0.0f;
            const float* rpb = embT + (lane << 4) + pass * 4;
            for (int dm = 0; dm < 8; ++dm) {
#pragma unroll
                for (int di = 0; di < 8; ++di) {
                    const int d = dm * 8 + di;
                    f32x4 ev = *(const f32x4*)(rpb + (size_t)d * KC);
#pragma unroll
                    for (int i = 0; i < 4; ++i) {
                        float xv = rdlane(xr[i], d);
                        acc[i * 4 + 0] = fmaf(xv, ev[0], acc[i * 4 + 0]);
                        acc[i * 4 + 1] = fmaf(xv, ev[1], acc[i * 4 + 1]);
                        acc[i * 4 + 2] = fmaf(xv, ev[2], acc[i * 4 + 2]);
                        acc[i * 4 + 3] = fmaf(xv, ev[3], acc[i * 4 + 3]);
                    }
                }
            }
#pragma unroll
            for (int j = 0; j < 4; ++j) {           // ascending k within lane
                int k = (lane << 4) + pass * 4 + j;
                float sek = se32[k];
#pragma unroll
                for (int i = 0; i < 4; ++i) {
                    float s = (sx4[i] + sek) - 2.0f * acc[i * 4 + j];   // filter only
                    if (s < m1[i]) {
                        m3[i] = m2[i]; m2[i] = m1[i]; i2[i] = i1[i];
                        m1[i] = s; i1[i] = k;
                    } else if (s < m2[i]) {
                        m3[i] = m2[i]; m2[i] = s; i2[i] = k;
                    } else if (s < m3[i]) {
                        m3[i] = s;
                    }
                }
            }
        }

        // per point: global f32 min -> verify explicit candidates -> writeback
#pragma unroll
        for (int i = 0; i < 4; ++i) {
            float gm = m1[i];
#pragma unroll
            for (int off = 1; off < 64; off <<= 1)
                gm = fminf(gm, __shfl_xor(gm, off));
            const float thr = gm + SLACKF;

            float bD = 3.4e38f; int bi = 0x7fffffff;
            if (m3[i] <= thr) {
                // ultra-rare: 3+ near-min codes in one lane -> exact-scan its 16
#pragma unroll 1
                for (int c = 0; c < 16; ++c) {
                    const int k = (lane << 4) + c;
                    float Dv = exact_dv(xr[i], emb, se32, sx4[i], k);
                    if (Dv < bD || (Dv == bD && k < bi)) { bD = Dv; bi = k; }
                }
            } else {
                if (m1[i] <= thr) {
                    const int k = i1[i];
                    float Dv = exact_dv(xr[i], emb, se32, sx4[i], k);
                    if (Dv < bD || (Dv == bD && k < bi)) { bD = Dv; bi = k; }
                }
                if (m2[i] <= thr) {
                    const int k = i2[i];
                    float Dv = exact_dv(xr[i], emb, se32, sx4[i], k);
                    if (Dv < bD || (Dv == bD && k < bi)) { bD = Dv; bi = k; }
                }
            }
#pragma unroll
            for (int off = 32; off > 0; off >>= 1) {
                float oD = __shfl_down(bD, off);
                int   oi = __shfl_down(bi, off);
                if (oD < bD || (oD == bD && oi < bi)) { bD = oD; bi = oi; }
            }
            bi = __shfl(bi, 0);                   // broadcast winner
            if (vld[i]) {
                int n = nn[i];
                int old = (int)outi[n];
                if (bi != old) {
                    int bb = n >> 12, hw = n & 4095;
                    float xv = xr[i];               // lane's own x[lane]
                    float qv = emb[bi * DD + lane];
                    float dv = qv - xv;
                    float l  = dv * dv;
                    outl[(size_t)n * DD + lane] = fmaf(0.25f, l, l);
                    outq[((size_t)bb * DD + lane) * HWSZ + hw] = xv + (qv - xv);
                    if (lane == 0) outi[n] = (float)bi;
                }
            }
        }
    }
}

extern "C" void kernel_launch(void* const* d_in, const int* in_sizes, int n_in,
                              void* d_out, int out_size, void* d_ws, size_t ws_size,
                              hipStream_t stream) {
    const float* in  = (const float*)d_in[0];   // (32,64,64,64) bchw f32
    const float* emb = (const float*)d_in[1];   // (1024,64) f32

    float* outq = (float*)d_out;                        // 8388608
    float* outl = outq + (size_t)NPTS * DD;             // 8388608
    float* outi = outl + (size_t)NPTS * DD;             // 131072 (idx as f32)

    char*   ws    = (char*)d_ws;                        // ~1.05 MB used
    float*  se32  = (float*)ws;                         // 4 KB
    float*  sebB  = (float*)(ws + 4096);                // 4 KB
    ushort* Ebuf  = (ushort*)(ws + 8192);               // 256 KB (frag-ordered hi/lo)
    float*  embT  = (float*)(ws + 8192 + 262144);       // 256 KB (d-major transpose)
    int*    cnt   = (int*)(ws + 8192 + 262144 + 262144);
    int*    queue = (int*)(ws + 8192 + 262144 + 262144 + 256);  // NPTS*4 worst case

    vq_prep_e<<<64, 256, 0, stream>>>(emb, se32, sebB, Ebuf, embT, cnt);
    vq_main<<<NPTS / 128, 256, 0, stream>>>(in, emb, Ebuf, sebB, outq, outl, outi, cnt, queue);
    vq_fix<<<2048, 256, 0, stream>>>(in, emb, embT, se32, queue, cnt, outq, outl, outi);
}

// Round 16
// 214.001 us; speedup vs baseline: 1.0541x; 1.0541x over previous
//
#include <hip/hip_runtime.h>

#define NPTS    131072     // 32 * 64 * 64 points
#define KC      1024       // codes
#define DD      64         // embedding dim
#define HWSZ    4096       // h*w
#define MARGINF 6e-5f      // packed-domain gap below which we refine on the f32 grid
#define SLACKF  4e-5f      // f32-filter slack >= 2*(chain err ~2e-6 + ulp(64) 7.6e-6)

typedef __attribute__((ext_vector_type(8))) short short8;  // 8 bf16 = 4 VGPRs
typedef __attribute__((ext_vector_type(4))) float f32x4;   // MFMA C/D frag

__device__ __forceinline__ ushort bf16_rne(float x) {
    unsigned u = __float_as_uint(x);
    unsigned r = u + 0x7fffu + ((u >> 16) & 1u);
    return (ushort)(r >> 16);
}

__device__ __forceinline__ float rdlane(float v, int d) {
    return __int_as_float(__builtin_amdgcn_readlane(__float_as_int(v), d));
}

// exact per-code grid value: ascending-d serial f64 fma chain + single rounding
// (bit-identical op order to the r3-verified vq_fix path).
__device__ __forceinline__ float exact_dv(float xrv, const float* __restrict__ emb,
                                          const float* __restrict__ se32,
                                          float sx, int k) {
    const float* er = emb + k * DD;
    double a = 0.0;
#pragma unroll 4
    for (int d = 0; d < DD; ++d)
        a = fma((double)rdlane(xrv, d), (double)er[d], a);
    float mm = (float)(2.0 * a);          // single rounding
    float s1, Dv;
    {
#pragma clang fp contract(off)
        s1 = sx + se32[k];
        Dv = s1 - mm;                     // the reference's f32 grid value
    }
    return Dv;
}

// ---- E prep: 64 blocks x 256 threads, one 16-code tile per block.
// All global loads/stores coalesced; ||e||^2 array-free in numpy pairwise order.
__global__ void __launch_bounds__(256)
vq_prep_e(const float* __restrict__ emb, float* __restrict__ se32,
          float* __restrict__ sebB, ushort* __restrict__ Ebuf,
          float* __restrict__ embT, int* __restrict__ cnt) {
    __shared__ float es[16][68];        // 16 codes x 64 dims, pad -> conflict-light
    const int tid  = threadIdx.x;       // 0..255
    const int tile = blockIdx.x;        // 64 tiles of 16 codes
    const int kbase = tile * 16;

    if (tile == 0 && tid == 0) *cnt = 0;   // replaces the memset dispatch

    // stage 16x64 floats coalesced (4 x 256 lanes, consecutive addresses)
#pragma unroll
    for (int it = 0; it < 4; ++it) {
        int f = it * 256 + tid;         // 0..1023
        es[f >> 6][f & 63] = emb[(size_t)kbase * DD + f];
    }
    __syncthreads();

    // ||e||^2: one thread per code, numpy pairwise order, registers only
    if (tid < 16) {
        float rr[8];
#pragma unroll
        for (int di = 0; di < 8; ++di) rr[di] = 0.0f;
        {
#pragma clang fp contract(off)
#pragma unroll
            for (int dm = 0; dm < 8; ++dm)
#pragma unroll
                for (int di = 0; di < 8; ++di) {
                    float ev = es[tid][dm * 8 + di];
                    rr[di] += ev * ev;      // 0+t == t bitwise (squares are +0-signed)
                }
        }
        float s;
        {
#pragma clang fp contract(off)
            s = ((rr[0] + rr[1]) + (rr[2] + rr[3])) + ((rr[4] + rr[5]) + (rr[6] + rr[7]));
        }
        se32[kbase + tid] = s;
        sebB[kbase + tid] = s + 0.5f;   // bias keeps scan scores strictly positive
    }

    // embT[d][k]: 1024 elems, 16-float runs contiguous -> well-coalesced
#pragma unroll
    for (int it = 0; it < 4; ++it) {
        int f = it * 256 + tid;
        int d = f >> 4, colk = f & 15;
        embT[d * KC + kbase + colk] = es[colk][d];
    }

    // Ebuf: 4 sub-blocks (kh,hl) x 512 ushorts, fully coalesced stores.
#pragma unroll
    for (int it = 0; it < 8; ++it) {
        int f = it * 256 + tid;         // 0..2047
        int sub = f >> 9;               // kh*2 + hl
        int pos = f & 511;
        int kh = sub >> 1, hl = sub & 1;
        int jj = pos & 7, colk = (pos >> 3) & 15, quad = pos >> 7;
        float ev = es[colk][kh * 32 + quad * 8 + jj];
        ushort hb = bf16_rne(ev);
        ushort val;
        if (hl == 0) {
            val = hb;
        } else {
            float hf = __uint_as_float(((unsigned)hb) << 16);
            val = bf16_rne(ev - hf);
        }
        Ebuf[((tile * 2 + kh) * 2 + hl) * 512 + pos] = val;
    }
}

// ---- fused: stage x -> A frags -> MFMA scan (packed-uint argmin) -> outputs
// (r14 form, verified twice at 98.5-100.3us. LDS B-staging variant (r15)
//  regressed to 113us: per-g barriers add vmcnt-drain stalls that outweigh
//  L2 savings — Ebuf is L2-broadcast-hot and its load latency was already
//  hidden by free-running waves. Do not re-stage B.)
__global__ void __launch_bounds__(256)
vq_main(const float* __restrict__ in, const float* __restrict__ emb,
        const ushort* __restrict__ Ebuf, const float* __restrict__ sebB,
        float* __restrict__ outq, float* __restrict__ outl, float* __restrict__ outi,
        int* __restrict__ cnt, int* __restrict__ queue) {
    __shared__ float xs[64][129];   // [c][j], pad -> conflict-light both ways (33 KB)
    __shared__ int   sidx[128];
    const int tid = threadIdx.x;
    const int n0  = blockIdx.x * 128;     // 128 consecutive points, single batch image
    const int b   = n0 >> 12;
    const int hw0 = n0 & 4095;
    const float* inb = in + (size_t)b * DD * HWSZ;

    // stage exact x for the block's 128 points (coalesced over hw)
#pragma unroll
    for (int it = 0; it < 32; ++it) {
        int f = tid + it * 256;
        int c = f >> 7, j = f & 127;
        xs[c][j] = inb[c * HWSZ + hw0 + j];
    }
    __syncthreads();

    const int lane = tid & 63, wave = tid >> 6;
    const int quad = lane >> 4, col = lane & 15;

    // A fragments (bf16 hi/lo) straight from LDS — no global X roundtrip
    short8 A[2][2][2];   // [psub][khalf][hi/lo]
#pragma unroll
    for (int p = 0; p < 2; ++p) {
        int pt = wave * 32 + p * 16 + col;
#pragma unroll
        for (int kh = 0; kh < 2; ++kh) {
            short8 ah, al;
#pragma unroll
            for (int j = 0; j < 8; ++j) {
                float xv = xs[kh * 32 + quad * 8 + j][pt];
                ushort hb = bf16_rne(xv);
                float  hf = __uint_as_float(((unsigned)hb) << 16);
                ah[j] = (short)hb;
                al[j] = (short)bf16_rne(xv - hf);
            }
            A[p][kh][0] = ah; A[p][kh][1] = al;
        }
    }

    unsigned b1[8], b2[8];          // packed: (score+0.5 bits & ~63) | tile
#pragma unroll
    for (int s = 0; s < 8; ++s) { b1[s] = 0xFFFFFFFFu; b2[s] = 0xFFFFFFFFu; }

    for (int g = 0; g < 16; ++g) {            // 64 codes per iteration
        short8 B[4][2][2];
        float  sB[4];
#pragma unroll
        for (int s = 0; s < 4; ++s) {
            int tile = g * 4 + s;
            sB[s] = sebB[tile * 16 + col];
#pragma unroll
            for (int kh = 0; kh < 2; ++kh)
#pragma unroll
                for (int hl = 0; hl < 2; ++hl)
                    B[s][kh][hl] = *(const short8*)(Ebuf + ((tile * 2 + kh) * 2 + hl) * 512 + lane * 8);
        }
        f32x4 acc[2][4];
#pragma unroll
        for (int p = 0; p < 2; ++p)
#pragma unroll
            for (int s = 0; s < 4; ++s) acc[p][s] = (f32x4){0.f, 0.f, 0.f, 0.f};
#pragma unroll
        for (int p = 0; p < 2; ++p)
#pragma unroll
            for (int s = 0; s < 4; ++s) {
                acc[p][s] = __builtin_amdgcn_mfma_f32_16x16x32_bf16(A[p][0][0], B[s][0][0], acc[p][s], 0, 0, 0);
                acc[p][s] = __builtin_amdgcn_mfma_f32_16x16x32_bf16(A[p][1][0], B[s][1][0], acc[p][s], 0, 0, 0);
                acc[p][s] = __builtin_amdgcn_mfma_f32_16x16x32_bf16(A[p][0][0], B[s][0][1], acc[p][s], 0, 0, 0);
                acc[p][s] = __builtin_amdgcn_mfma_f32_16x16x32_bf16(A[p][1][0], B[s][1][1], acc[p][s], 0, 0, 0);
                acc[p][s] = __builtin_amdgcn_mfma_f32_16x16x32_bf16(A[p][0][1], B[s][0][0], acc[p][s], 0, 0, 0);
                acc[p][s] = __builtin_amdgcn_mfma_f32_16x16x32_bf16(A[p][1][1], B[s][1][0], acc[p][s], 0, 0, 0);
            }
        // packed-uint fold: 4 codes per slot via sorted-2-of-4 insertion
#pragma unroll
        for (int p = 0; p < 2; ++p)
#pragma unroll
            for (int r = 0; r < 4; ++r) {
                unsigned q[4];
#pragma unroll
                for (int s = 0; s < 4; ++s) {
                    float t = fmaf(-2.f, acc[p][s][r], sB[s]);       // 0.5 + se - 2x.e > 0
                    q[s] = (__float_as_uint(t) & 0xFFFFFFC0u) | (unsigned)(g * 4 + s);
                }
                unsigned a  = min(q[0], q[1]), bb = max(q[0], q[1]);
                unsigned c2 = min(q[2], q[3]), d2 = max(q[2], q[3]);
                unsigned lo = min(a, c2), hi = max(a, c2);
                unsigned sec = min(min(bb, d2), hi);                  // 2nd smallest of 4
                int sl = p * 4 + r;
                b2[sl] = min(min(b2[sl], sec), max(b1[sl], lo));
                b1[sl] = min(b1[sl], lo);
            }
    }

    // decode + 16-col butterfly merge (first-index tie-break)
    unsigned v1[8], v2[8]; int ci[8];
#pragma unroll
    for (int s = 0; s < 8; ++s) {
        ci[s] = (int)(b1[s] & 63u) * 16 + col;
        v1[s] = b1[s] & 0xFFFFFFC0u;
        v2[s] = b2[s] & 0xFFFFFFC0u;
    }
#pragma unroll
    for (int off = 1; off < 16; off <<= 1) {
#pragma unroll
        for (int s = 0; s < 8; ++s) {
            unsigned o1 = (unsigned)__shfl_xor((int)v1[s], off);
            unsigned o2 = (unsigned)__shfl_xor((int)v2[s], off);
            int      oi = __shfl_xor(ci[s], off);
            unsigned nb2 = min(min(v2[s], o2), max(v1[s], o1));
            bool take = (o1 < v1[s]) || (o1 == v1[s] && oi < ci[s]);
            v1[s] = take ? o1 : v1[s];
            ci[s] = take ? oi : ci[s];
            v2[s] = nb2;
        }
    }
#pragma unroll
    for (int s = 0; s < 8; ++s) {
        if (col == s) {
            int jloc = wave * 32 + (s >> 2) * 16 + quad * 4 + (s & 3);
            sidx[jloc] = ci[s];
            float f1 = __uint_as_float(v1[s]), f2 = __uint_as_float(v2[s]);
            if (f2 - f1 < MARGINF) { int pos = atomicAdd(cnt, 1); queue[pos] = n0 + jloc; }
        }
    }
    __syncthreads();

    // fused output epilogue: lane -> channel, loop over this wave's 32 points
    for (int t = 0; t < 32; ++t) {
        int jloc = wave * 32 + t;
        int kidx = sidx[jloc];
        float qv = emb[kidx * DD + lane];              // coalesced 256B row, L2-hot
        float x  = xs[lane][jloc];
        float dv = qv - x;
        float l  = dv * dv;
        outl[(size_t)(n0 + jloc) * DD + lane] = fmaf(0.25f, l, l);   // coalesced
        outq[((size_t)(b * DD) + lane) * HWSZ + hw0 + jloc] = x + (qv - x);  // L2-merged scatter
    }
    if (lane < 32) outi[n0 + wave * 32 + lane] = (float)sidx[wave * 32 + lane];
}

// ---- fix v4: f32 filter with per-lane TOP-3 tracking -> explicit candidates
// {i1,i2} (<= gmin+SLACK) verified by the bit-exact serial f64 chain; full-16
// per-lane fallback only if m3 <= thr. Grid 2048 blocks.
__global__ void __launch_bounds__(256)
vq_fix(const float* __restrict__ in, const float* __restrict__ emb,
       const float* __restrict__ embT, const float* __restrict__ se32,
       const int* __restrict__ queue, const int* __restrict__ cnt,
       float* __restrict__ outq, float* __restrict__ outl, float* __restrict__ outi) {
    const int lane = threadIdx.x & 63;
    const int gw   = blockIdx.x * 4 + (threadIdx.x >> 6);
    const int nwav = gridDim.x * 4;
    const int total = *cnt;
    for (int q0 = gw * 4; q0 < total; q0 += nwav * 4) {
        int   nn[4]; bool vld[4];
        float xr[4], sx4[4];
#pragma unroll
        for (int i = 0; i < 4; ++i) {
            int qi = q0 + i;
            vld[i] = (qi < total);
            nn[i]  = queue[vld[i] ? qi : q0];
            int b = nn[i] >> 12, hw = nn[i] & 4095;
            xr[i] = in[(size_t)b * DD * HWSZ + (size_t)lane * HWSZ + hw]; // lane d holds x[d]
        }
        // ||x||^2 per point, numpy pairwise order (readlane ascending d) — exact
#pragma unroll
        for (int i = 0; i < 4; ++i) {
            float rr[8];
#pragma unroll
            for (int di = 0; di < 8; ++di) rr[di] = 0.0f;
            for (int dm = 0; dm < 8; ++dm) {
#pragma unroll
                for (int di = 0; di < 8; ++di) {
                    float xv = rdlane(xr[i], dm * 8 + di);
                    {
#pragma clang fp contract(off)
                        rr[di] += xv * xv;     // +0 init: 0+t == t bitwise, order kept
                    }
                }
            }
            {
#pragma clang fp contract(off)
                sx4[i] = ((rr[0] + rr[1]) + (rr[2] + rr[3])) + ((rr[4] + rr[5]) + (rr[6] + rr[7]));
            }
        }

        float m1[4], m2[4], m3[4]; int i1[4], i2[4];
#pragma unroll
        for (int i = 0; i < 4; ++i) {
            m1[i] = 3.4e38f; m2[i] = 3.4e38f; m3[i] = 3.4e38f;
            i1[i] = 0x7fffffff; i2[i] = 0x7fffffff;
        }

        // f32 filter: 4 passes of 4 codes/lane; 16 live f32 accumulators
        for (int pass = 0; pass < 4; ++pass) {
            float acc[16];
#pragma unroll
            for (int a = 0; a < 16; ++a) acc[a] = 0.0f;
            const float* rpb = embT + (lane << 4) + pass * 4;
            for (int dm = 0; dm < 8; ++dm) {
#pragma unroll
                for (int di = 0; di < 8; ++di) {
                    const int d = dm * 8 + di;
                    f32x4 ev = *(const f32x4*)(rpb + (size_t)d * KC);
#pragma unroll
                    for (int i = 0; i < 4; ++i) {
                        float xv = rdlane(xr[i], d);
                        acc[i * 4 + 0] = fmaf(xv, ev[0], acc[i * 4 + 0]);
                        acc[i * 4 + 1] = fmaf(xv, ev[1], acc[i * 4 + 1]);
                        acc[i * 4 + 2] = fmaf(xv, ev[2], acc[i * 4 + 2]);
                        acc[i * 4 + 3] = fmaf(xv, ev[3], acc[i * 4 + 3]);
                    }
                }
            }
#pragma unroll
            for (int j = 0; j < 4; ++j) {           // ascending k within lane
                int k = (lane << 4) + pass * 4 + j;
                float sek = se32[k];
#pragma unroll
                for (int i = 0; i < 4; ++i) {
                    float s = (sx4[i] + sek) - 2.0f * acc[i * 4 + j];   // filter only
                    if (s < m1[i]) {
                        m3[i] = m2[i]; m2[i] = m1[i]; i2[i] = i1[i];
                        m1[i] = s; i1[i] = k;
                    } else if (s < m2[i]) {
                        m3[i] = m2[i]; m2[i] = s; i2[i] = k;
                    } else if (s < m3[i]) {
                        m3[i] = s;
                    }
                }
            }
        }

        // per point: global f32 min -> verify explicit candidates -> writeback
#pragma unroll
        for (int i = 0; i < 4; ++i) {
            float gm = m1[i];
#pragma unroll
            for (int off = 1; off < 64; off <<= 1)
                gm = fminf(gm, __shfl_xor(gm, off));
            const float thr = gm + SLACKF;

            float bD = 3.4e38f; int bi = 0x7fffffff;
            if (m3[i] <= thr) {
                // ultra-rare: 3+ near-min codes in one lane -> exact-scan its 16
#pragma unroll 1
                for (int c = 0; c < 16; ++c) {
                    const int k = (lane << 4) + c;
                    float Dv = exact_dv(xr[i], emb, se32, sx4[i], k);
                    if (Dv < bD || (Dv == bD && k < bi)) { bD = Dv; bi = k; }
                }
            } else {
                if (m1[i] <= thr) {
                    const int k = i1[i];
                    float Dv = exact_dv(xr[i], emb, se32, sx4[i], k);
                    if (Dv < bD || (Dv == bD && k < bi)) { bD = Dv; bi = k; }
                }
                if (m2[i] <= thr) {
                    const int k = i2[i];
                    float Dv = exact_dv(xr[i], emb, se32, sx4[i], k);
                    if (Dv < bD || (Dv == bD && k < bi)) { bD = Dv; bi = k; }
                }
            }
#pragma unroll
            for (int off = 32; off > 0; off >>= 1) {
                float oD = __shfl_down(bD, off);
                int   oi = __shfl_down(bi, off);
                if (oD < bD || (oD == bD && oi < bi)) { bD = oD; bi = oi; }
            }
            bi = __shfl(bi, 0);                   // broadcast winner
            if (vld[i]) {
                int n = nn[i];
                int old = (int)outi[n];
                if (bi != old) {
                    int bb = n >> 12, hw = n & 4095;
                    float xv = xr[i];               // lane's own x[lane]
                    float qv = emb[bi * DD + lane];
                    float dv = qv - xv;
                    float l  = dv * dv;
                    outl[(size_t)n * DD + lane] = fmaf(0.25f, l, l);
                    outq[((size_t)bb * DD + lane) * HWSZ + hw] = xv + (qv - xv);
                    if (lane == 0) outi[n] = (float)bi;
                }
            }
        }
    }
}

extern "C" void kernel_launch(void* const* d_in, const int* in_sizes, int n_in,
                              void* d_out, int out_size, void* d_ws, size_t ws_size,
                              hipStream_t stream) {
    const float* in  = (const float*)d_in[0];   // (32,64,64,64) bchw f32
    const float* emb = (const float*)d_in[1];   // (1024,64) f32

    float* outq = (float*)d_out;                        // 8388608
    float* outl = outq + (size_t)NPTS * DD;             // 8388608
    float* outi = outl + (size_t)NPTS * DD;             // 131072 (idx as f32)

    char*   ws    = (char*)d_ws;                        // ~1.05 MB used
    float*  se32  = (float*)ws;                         // 4 KB
    float*  sebB  = (float*)(ws + 4096);                // 4 KB
    ushort* Ebuf  = (ushort*)(ws + 8192);               // 256 KB (frag-ordered hi/lo)
    float*  embT  = (float*)(ws + 8192 + 262144);       // 256 KB (d-major transpose)
    int*    cnt   = (int*)(ws + 8192 + 262144 + 262144);
    int*    queue = (int*)(ws + 8192 + 262144 + 262144 + 256);  // NPTS*4 worst case

    vq_prep_e<<<64, 256, 0, stream>>>(emb, se32, sebB, Ebuf, embT, cnt);
    vq_main<<<NPTS / 128, 256, 0, stream>>>(in, emb, Ebuf, sebB, outq, outl, outi, cnt, queue);
    vq_fix<<<2048, 256, 0, stream>>>(in, emb, embT, se32, queue, cnt, outq, outl, outi);
}